// Round 19
// baseline (204.332 us; speedup 1.0000x reference)
//
// CategoryAttention (softmax over HEADS axis). Round 19.
// = round 18 (190us best) with pass_b widened to 32q/wave (256q/block, grid 256):
// 2 q-groups per wave (r6-proven g-indexing), V-frags shared across groups.
// Doubles MFMA per barrier interval (16->32) at ~fixed per-iter chain cost.
// LDS 68KB (r10-proven size); VGPR ~180 <= 256 cap for 2 waves/SIMD residency.
// Everything else identical to round 18.
#include <hip/hip_runtime.h>
#include <hip/hip_bf16.h>
#include <hip/hip_fp16.h>

#define DM 1024
#define NH 16
#define HD 64
#define LL 2048

typedef __attribute__((ext_vector_type(8))) short bf16x8;
typedef __attribute__((ext_vector_type(4))) float f32x4;

#define MFMA16(a,b,c) __builtin_amdgcn_mfma_f32_16x16x32_bf16((a),(b),(c),0,0,0)

// async global->LDS, 16B per lane; dst wave-uniform, src per-lane.
#define GL16(g, l) __builtin_amdgcn_global_load_lds( \
    (const __attribute__((address_space(1))) unsigned int*)(g), \
    (__attribute__((address_space(3))) unsigned int*)(l), 16, 0, 0)

__device__ __forceinline__ ushort f2bf(float f) {
  union { float f; unsigned int u; } v; v.f = f;
  unsigned int u = v.u + 0x7fffu + ((v.u >> 16) & 1u);
  return (ushort)(u >> 16);
}

// ---- batched fp32 -> bf16 convert over up to 7 regions (one launch) ----
__global__ __launch_bounds__(256) void cvt7(const float* __restrict__ s0, ushort* __restrict__ d0, int n0,
                                            const float* __restrict__ s1, ushort* __restrict__ d1, int n1,
                                            const float* __restrict__ s2, ushort* __restrict__ d2, int n2,
                                            const float* __restrict__ s3, ushort* __restrict__ d3, int n3,
                                            const float* __restrict__ s4, ushort* __restrict__ d4, int n4,
                                            const float* __restrict__ s5, ushort* __restrict__ d5, int n5,
                                            const float* __restrict__ s6, ushort* __restrict__ d6, int n6) {
  int i = (blockIdx.x * 256 + threadIdx.x) * 4;
  const float* s; ushort* d;
  if (i < n0) { s = s0; d = d0; }
  else if ((i -= n0) < n1) { s = s1; d = d1; }
  else if ((i -= n1) < n2) { s = s2; d = d2; }
  else if ((i -= n2) < n3) { s = s3; d = d3; }
  else if ((i -= n3) < n4) { s = s4; d = d4; }
  else if ((i -= n4) < n5) { s = s5; d = d5; }
  else if ((i -= n5) < n6) { s = s6; d = d6; }
  else return;
  float4 v = *(const float4*)(s + i);
  union { ushort u[4]; unsigned long long ll; } o;
  o.u[0] = f2bf(v.x); o.u[1] = f2bf(v.y); o.u[2] = f2bf(v.z); o.u[3] = f2bf(v.w);
  *(unsigned long long*)(d + i) = o.ll;
}

// ---- fused QKV projection GEMM, 128x128 tile ----
// z=0 Q (alpha=0.125), z=1 K, z=2 V (transposed out).
__global__ __launch_bounds__(256) void gemm_qkv(const ushort* __restrict__ qA, const ushort* __restrict__ qW,
                                                const float* __restrict__ qb, ushort* __restrict__ qO,
                                                const ushort* __restrict__ kA, const ushort* __restrict__ kW,
                                                const float* __restrict__ kb, ushort* __restrict__ kO,
                                                const ushort* __restrict__ vA, const ushort* __restrict__ vW,
                                                const float* __restrict__ vb, ushort* __restrict__ vO) {
  __shared__ ushort lA[2][128][64];
  __shared__ ushort lB[2][128][64];
  const int z = blockIdx.z;
  const ushort* Ab; const ushort* Wb; const float* bias; ushort* outp;
  float alpha; bool trans;
  if (z == 0)      { Ab = qA; Wb = qW; bias = qb; outp = qO; alpha = 0.125f; trans = false; }
  else if (z == 1) { Ab = kA; Wb = kW; bias = kb; outp = kO; alpha = 1.0f;   trans = false; }
  else             { Ab = vA; Wb = vW; bias = vb; outp = vO; alpha = 1.0f;   trans = true;  }

  const int m0 = blockIdx.x * 128, n0 = blockIdx.y * 128;
  const int t = threadIdx.x;
  const int w = t >> 6, lane = t & 63, lr = lane & 15, lg = lane >> 4;
  const int wm = (w >> 1) * 64, wn = (w & 1) * 64;
  const int lrow8 = lane >> 3;
  const int scol = ((lane & 7) ^ lrow8) * 8;

  f32x4 acc[4][4];
  #pragma unroll
  for (int i = 0; i < 4; ++i)
    #pragma unroll
    for (int j = 0; j < 4; ++j) acc[i][j] = (f32x4){0.f, 0.f, 0.f, 0.f};

  #pragma unroll
  for (int c = 0; c < 4; ++c) {
    GL16(Ab + (m0 + w * 32 + c * 8 + lrow8) * DM + scol, &lA[0][w * 32 + c * 8][0]);
    GL16(Wb + (n0 + w * 32 + c * 8 + lrow8) * DM + scol, &lB[0][w * 32 + c * 8][0]);
  }
  __syncthreads();

  int cur = 0;
  for (int k0 = 0; k0 < DM; k0 += 64) {
    if (k0 + 64 < DM) {
      #pragma unroll
      for (int c = 0; c < 4; ++c) {
        GL16(Ab + (m0 + w * 32 + c * 8 + lrow8) * DM + k0 + 64 + scol, &lA[cur ^ 1][w * 32 + c * 8][0]);
        GL16(Wb + (n0 + w * 32 + c * 8 + lrow8) * DM + k0 + 64 + scol, &lB[cur ^ 1][w * 32 + c * 8][0]);
      }
    }
    #pragma unroll
    for (int ks = 0; ks < 2; ++ks) {
      bf16x8 aF[4], bF[4];
      #pragma unroll
      for (int i = 0; i < 4; ++i)
        aF[i] = *(const bf16x8*)&lA[cur][wm + i * 16 + lr][(((ks * 4 + lg) ^ (lr & 7)) * 8)];
      #pragma unroll
      for (int j = 0; j < 4; ++j)
        bF[j] = *(const bf16x8*)&lB[cur][wn + j * 16 + lr][(((ks * 4 + lg) ^ (lr & 7)) * 8)];
      #pragma unroll
      for (int i = 0; i < 4; ++i)
        #pragma unroll
        for (int j = 0; j < 4; ++j)
          acc[i][j] = MFMA16(aF[i], bF[j], acc[i][j]);
    }
    __syncthreads();
    cur ^= 1;
  }

  #pragma unroll
  for (int i = 0; i < 4; ++i)
    #pragma unroll
    for (int j = 0; j < 4; ++j)
      #pragma unroll
      for (int r = 0; r < 4; ++r) {
        int m = m0 + wm + i * 16 + lg * 4 + r;
        int n = n0 + wn + j * 16 + lr;
        float v = (acc[i][j][r] + bias[n]) * alpha;
        int b = m >> 11, q = m & 2047, h = n >> 6, d = n & 63;
        if (!trans)
          outp[((b * NH + h) * LL + q) * HD + d] = f2bf(v);
        else
          outp[((b * NH + h) * HD + d) * LL + q] = f2bf(v);
      }
}

// ---- output GEMM: 64x128 tile, fp32 out ----
__global__ __launch_bounds__(256) void gemm_out(const ushort* __restrict__ Ab,
                                                const ushort* __restrict__ Wb,
                                                const float* __restrict__ bias,
                                                float* __restrict__ outf) {
  __shared__ ushort lA[2][64][64];
  __shared__ ushort lB[2][128][64];
  const int m0 = blockIdx.x * 64, n0 = blockIdx.y * 128;
  const int t = threadIdx.x;
  const int w = t >> 6, lane = t & 63, lr = lane & 15, lg = lane >> 4;
  const int wm = (w >> 1) * 32, wn = (w & 1) * 64;
  const int lrow8 = lane >> 3;
  const int scol = ((lane & 7) ^ lrow8) * 8;

  f32x4 acc[2][4];
  #pragma unroll
  for (int i = 0; i < 2; ++i)
    #pragma unroll
    for (int j = 0; j < 4; ++j) acc[i][j] = (f32x4){0.f, 0.f, 0.f, 0.f};

  #pragma unroll
  for (int c = 0; c < 2; ++c)
    GL16(Ab + (m0 + w * 16 + c * 8 + lrow8) * DM + scol, &lA[0][w * 16 + c * 8][0]);
  #pragma unroll
  for (int c = 0; c < 4; ++c)
    GL16(Wb + (n0 + w * 32 + c * 8 + lrow8) * DM + scol, &lB[0][w * 32 + c * 8][0]);
  __syncthreads();

  int cur = 0;
  for (int k0 = 0; k0 < DM; k0 += 64) {
    if (k0 + 64 < DM) {
      #pragma unroll
      for (int c = 0; c < 2; ++c)
        GL16(Ab + (m0 + w * 16 + c * 8 + lrow8) * DM + k0 + 64 + scol, &lA[cur ^ 1][w * 16 + c * 8][0]);
      #pragma unroll
      for (int c = 0; c < 4; ++c)
        GL16(Wb + (n0 + w * 32 + c * 8 + lrow8) * DM + k0 + 64 + scol, &lB[cur ^ 1][w * 32 + c * 8][0]);
    }
    #pragma unroll
    for (int ks = 0; ks < 2; ++ks) {
      bf16x8 aF[2], bF[4];
      #pragma unroll
      for (int i = 0; i < 2; ++i)
        aF[i] = *(const bf16x8*)&lA[cur][wm + i * 16 + lr][(((ks * 4 + lg) ^ (lr & 7)) * 8)];
      #pragma unroll
      for (int j = 0; j < 4; ++j)
        bF[j] = *(const bf16x8*)&lB[cur][wn + j * 16 + lr][(((ks * 4 + lg) ^ (lr & 7)) * 8)];
      #pragma unroll
      for (int i = 0; i < 2; ++i)
        #pragma unroll
        for (int j = 0; j < 4; ++j)
          acc[i][j] = MFMA16(aF[i], bF[j], acc[i][j]);
    }
    __syncthreads();
    cur ^= 1;
  }

  #pragma unroll
  for (int i = 0; i < 2; ++i)
    #pragma unroll
    for (int j = 0; j < 4; ++j)
      #pragma unroll
      for (int r = 0; r < 4; ++r) {
        int m = m0 + wm + i * 16 + lg * 4 + r;
        int n = n0 + wn + j * 16 + lr;
        outf[m * DM + n] = acc[i][j][r] + bias[n];
      }
}

// ---- Pass A (MFMA, swapped): rdenH[b][q][k] = 1 / sum_h exp(<Qh,Kh>) ----
// + XCD-bijective swizzle (4 q-rows x 16 k-cols per XCD -> panels L2-resident)
__global__ __launch_bounds__(256) void pass_a_m(const ushort* __restrict__ Qh,
                                                const ushort* __restrict__ Kh,
                                                __half* __restrict__ rdenH) {
  __shared__ ushort lQ[2][128][64];
  __shared__ ushort lK[2][128][64];
  const int fid = blockIdx.x + 16 * (blockIdx.y + 16 * blockIdx.z);
  const int nid = (fid & 7) * 64 + (fid >> 3);
  const int k0 = (nid & 15) * 128;
  const int q0 = ((nid >> 4) & 15) * 128;
  const int b  = nid >> 8;
  const int t = threadIdx.x, w = t >> 6, lane = t & 63, lr = lane & 15, lg = lane >> 4;
  const int lrow8 = lane >> 3;
  const int scol = ((lane & 7) ^ lrow8) * 8;

  f32x4 acc[2][8];
  #pragma unroll
  for (int i = 0; i < 2; ++i)
    #pragma unroll
    for (int j = 0; j < 8; ++j) acc[i][j] = (f32x4){0.f, 0.f, 0.f, 0.f};

  #pragma unroll
  for (int c = 0; c < 4; ++c) {
    GL16(Qh + ((b * NH) * LL + q0 + w * 32 + c * 8 + lrow8) * HD + scol, &lQ[0][w * 32 + c * 8][0]);
    GL16(Kh + ((b * NH) * LL + k0 + w * 32 + c * 8 + lrow8) * HD + scol, &lK[0][w * 32 + c * 8][0]);
  }
  __syncthreads();

  int cur = 0;
  for (int h = 0; h < NH; ++h) {
    if (h + 1 < NH) {
      #pragma unroll
      for (int c = 0; c < 4; ++c) {
        GL16(Qh + ((b * NH + h + 1) * LL + q0 + w * 32 + c * 8 + lrow8) * HD + scol, &lQ[cur ^ 1][w * 32 + c * 8][0]);
        GL16(Kh + ((b * NH + h + 1) * LL + k0 + w * 32 + c * 8 + lrow8) * HD + scol, &lK[cur ^ 1][w * 32 + c * 8][0]);
      }
    }
    #pragma unroll
    for (int i = 0; i < 2; ++i) {
      int qrow = w * 32 + i * 16 + lr;
      bf16x8 a0 = *(const bf16x8*)&lQ[cur][qrow][((lg ^ (lr & 7)) * 8)];
      bf16x8 a1 = *(const bf16x8*)&lQ[cur][qrow][(((4 + lg) ^ (lr & 7)) * 8)];
      #pragma unroll
      for (int j = 0; j < 8; ++j) {
        int krow = j * 16 + lr;
        bf16x8 b0 = *(const bf16x8*)&lK[cur][krow][((lg ^ (lr & 7)) * 8)];
        bf16x8 b1 = *(const bf16x8*)&lK[cur][krow][(((4 + lg) ^ (lr & 7)) * 8)];
        f32x4 e = {0.f, 0.f, 0.f, 0.f};
        e = MFMA16(b0, a0, e);   // swapped: D[k][q]
        e = MFMA16(b1, a1, e);
        #pragma unroll
        for (int r = 0; r < 4; ++r) acc[i][j][r] += __expf(e[r]);
      }
    }
    __syncthreads();
    cur ^= 1;
  }

  #pragma unroll
  for (int i = 0; i < 2; ++i)
    #pragma unroll
    for (int j = 0; j < 8; ++j) {
      int q = q0 + w * 32 + i * 16 + lr;
      int k = k0 + j * 16 + lg * 4;
      union { __half2 h2[2]; uint2 u; } pk;
      pk.h2[0] = __floats2half2_rn(__builtin_amdgcn_rcpf(acc[i][j][0]),
                                   __builtin_amdgcn_rcpf(acc[i][j][1]));
      pk.h2[1] = __floats2half2_rn(__builtin_amdgcn_rcpf(acc[i][j][2]),
                                   __builtin_amdgcn_rcpf(acc[i][j][3]));
      *(uint2*)&rdenH[(size_t)(b * LL + q) * LL + k] = pk.u;
    }
}

// ---- Pass B: 8 waves x 32q (2 groups of 16), 2-stage pipeline ----
// Wave w owns q rows [w*32, w*32+32); V-frags shared across groups.
#define PB_BODY(PH)                                                              \
  {                                                                              \
    const int T = tt + PH;                                                       \
    const int k0 = T * 64;                                                       \
    uint2 rdN[2][4];                                                             \
    if (T + 1 < 32) {                                                            \
      GL16(Kh + (bh * LL + k0 + 64 + w * 8 + lrow8) * HD + scol,                 \
           &lK[PH ^ 1][w * 8][0]);                                               \
      GL16(Vt + (bh * HD + w * 8 + lrow8) * LL + k0 + 64 + scol,                 \
           &lV[PH ^ 1][w * 8][0]);                                               \
      _Pragma("unroll")                                                          \
      for (int g = 0; g < 2; ++g)                                                \
        _Pragma("unroll")                                                        \
        for (int j = 0; j < 4; ++j)                                              \
          rdN[g][j] = *(const uint2*)(rrow[g] + k0 + 64 + j * 16 + lg * 4);      \
    }                                                                            \
    __builtin_amdgcn_s_setprio(1);                                               \
    if (T > 0) {                                                                 \
      _Pragma("unroll")                                                          \
      for (int g = 0; g < 2; ++g) {                                              \
        bf16x8 aP0 = *(const bf16x8*)&U.p[w][g * 16 + lr][lg * 8];               \
        bf16x8 aP1 = *(const bf16x8*)&U.p[w][g * 16 + lr][32 + lg * 8];          \
        _Pragma("unroll")                                                        \
        for (int j = 0; j < 4; ++j) {                                            \
          accO[g][j] = MFMA16(aP0, vF0[j], accO[g][j]);                          \
          accO[g][j] = MFMA16(aP1, vF1[j], accO[g][j]);                          \
        }                                                                        \
      }                                                                          \
    }                                                                            \
    f32x4 e[2][4];                                                               \
    _Pragma("unroll")                                                            \
    for (int j = 0; j < 4; ++j) {                                                \
      int krow = j * 16 + lr;                                                    \
      bf16x8 kf0 = *(const bf16x8*)&lK[PH][krow][((lg ^ (lr & 7)) * 8)];         \
      bf16x8 kf1 = *(const bf16x8*)&lK[PH][krow][(((4 + lg) ^ (lr & 7)) * 8)];   \
      _Pragma("unroll")                                                          \
      for (int g = 0; g < 2; ++g) {                                              \
        e[g][j] = (f32x4){0.f, 0.f, 0.f, 0.f};                                   \
        e[g][j] = MFMA16(kf0, aQ0[g], e[g][j]);                                  \
        e[g][j] = MFMA16(kf1, aQ1[g], e[g][j]);                                  \
      }                                                                          \
    }                                                                            \
    __builtin_amdgcn_s_setprio(0);                                               \
    _Pragma("unroll")                                                            \
    for (int j = 0; j < 4; ++j) {                                                \
      int vrow = j * 16 + lr;                                                    \
      vF0[j] = *(const bf16x8*)&lV[PH][vrow][((lg ^ (lr & 7)) * 8)];             \
      vF1[j] = *(const bf16x8*)&lV[PH][vrow][(((4 + lg) ^ (lr & 7)) * 8)];       \
    }                                                                            \
    _Pragma("unroll")                                                            \
    for (int g = 0; g < 2; ++g)                                                  \
      _Pragma("unroll")                                                          \
      for (int j = 0; j < 4; ++j) {                                              \
        float2 f0 = __half22float2(*reinterpret_cast<const __half2*>(&rdC[g][j].x)); \
        float2 f1 = __half22float2(*reinterpret_cast<const __half2*>(&rdC[g][j].y)); \
        union { __hip_bfloat162 b2[2]; uint2 u; } pk;                            \
        pk.b2[0] = __float22bfloat162_rn(make_float2(__expf(e[g][j][0]) * f0.x,  \
                                                     __expf(e[g][j][1]) * f0.y));\
        pk.b2[1] = __float22bfloat162_rn(make_float2(__expf(e[g][j][2]) * f1.x,  \
                                                     __expf(e[g][j][3]) * f1.y));\
        *(uint2*)&U.p[w][g * 16 + lr][j * 16 + lg * 4] = pk.u;                   \
      }                                                                          \
    if (T + 1 < 32) {                                                            \
      _Pragma("unroll")                                                          \
      for (int g = 0; g < 2; ++g)                                                \
        _Pragma("unroll")                                                        \
        for (int j = 0; j < 4; ++j) rdC[g][j] = rdN[g][j];                       \
    }                                                                            \
    __syncthreads();                                                             \
  }

__global__ __launch_bounds__(512) void pass_b_m(const ushort* __restrict__ Qh,
                                                const ushort* __restrict__ Kh,
                                                const ushort* __restrict__ Vt,
                                                const __half* __restrict__ rdenH,
                                                ushort* __restrict__ AO) {
  __shared__ union UQP { ushort q[256][64]; ushort p[8][32][72]; } U;
  __shared__ ushort lK[2][64][64];
  __shared__ ushort lV[2][64][64];
  // XCD-bijective swizzle: 256 blocks (256%8==0), 2 heads per XCD chunk.
  const int fid = blockIdx.x + 8 * (blockIdx.y + NH * blockIdx.z);
  const int nid = (fid & 7) * 32 + (fid >> 3);
  const int q0 = (nid & 7) * 256;
  const int h  = (nid >> 3) & 15;
  const int b  = nid >> 7;
  const int t = threadIdx.x, w = t >> 6, lane = t & 63, lr = lane & 15, lg = lane >> 4;
  const int lrow8 = lane >> 3;
  const int scol = ((lane & 7) ^ lrow8) * 8;
  const int bh = b * NH + h;

  // stage Q (256 rows, linear)
  #pragma unroll
  for (int u = 0; u < 4; ++u) {
    int c = u * 512 + t;
    int row = c >> 3, col = (c & 7) * 8;
    *(bf16x8*)&U.q[row][col] = *(const bf16x8*)&Qh[(bh * LL + q0 + row) * HD + col];
  }
  // prologue K/V tile 0: wave w stages rows [w*8, w*8+8)
  GL16(Kh + (bh * LL + w * 8 + lrow8) * HD + scol, &lK[0][w * 8][0]);
  GL16(Vt + (bh * HD + w * 8 + lrow8) * LL + scol, &lV[0][w * 8][0]);
  // rden prologue (tile 0), per group
  const __half* rrow[2];
  rrow[0] = rdenH + (size_t)(b * LL + q0 + w * 32 + lr) * LL;
  rrow[1] = rdenH + (size_t)(b * LL + q0 + w * 32 + 16 + lr) * LL;
  uint2 rdC[2][4];
  #pragma unroll
  for (int g = 0; g < 2; ++g)
    #pragma unroll
    for (int j = 0; j < 4; ++j) rdC[g][j] = *(const uint2*)(rrow[g] + j * 16 + lg * 4);
  __syncthreads();

  bf16x8 aQ0[2], aQ1[2];
  #pragma unroll
  for (int g = 0; g < 2; ++g) {
    aQ0[g] = *(const bf16x8*)&U.q[w * 32 + g * 16 + lr][lg * 8];
    aQ1[g] = *(const bf16x8*)&U.q[w * 32 + g * 16 + lr][32 + lg * 8];
  }
  __syncthreads();   // Q reads complete before any U.p write

  f32x4 accO[2][4];
  #pragma unroll
  for (int g = 0; g < 2; ++g)
    #pragma unroll
    for (int j = 0; j < 4; ++j) accO[g][j] = (f32x4){0.f, 0.f, 0.f, 0.f};
  bf16x8 vF0[4], vF1[4];

  for (int tt = 0; tt < 32; tt += 2) {
    PB_BODY(0)
    PB_BODY(1)
  }

  // drain: PV(31) -- P in U.p, V frags in regs
  #pragma unroll
  for (int g = 0; g < 2; ++g) {
    bf16x8 aP0 = *(const bf16x8*)&U.p[w][g * 16 + lr][lg * 8];
    bf16x8 aP1 = *(const bf16x8*)&U.p[w][g * 16 + lr][32 + lg * 8];
    #pragma unroll
    for (int j = 0; j < 4; ++j) {
      accO[g][j] = MFMA16(aP0, vF0[j], accO[g][j]);
      accO[g][j] = MFMA16(aP1, vF1[j], accO[g][j]);
    }
  }

  #pragma unroll
  for (int g = 0; g < 2; ++g)
    #pragma unroll
    for (int j = 0; j < 4; ++j)
      #pragma unroll
      for (int r = 0; r < 4; ++r) {
        int q = q0 + w * 32 + g * 16 + lg * 4 + r;
        int d = j * 16 + lr;
        AO[(size_t)(b * LL + q) * DM + h * HD + d] = f2bf(accO[g][j][r]);
      }
}

extern "C" void kernel_launch(void* const* d_in, const int* in_sizes, int n_in,
                              void* d_out, int out_size, void* d_ws, size_t ws_size,
                              hipStream_t stream) {
  const float* query = (const float*)d_in[0];
  const float* key   = (const float*)d_in[1];
  const float* value = (const float*)d_in[2];
  const float* Wq_w  = (const float*)d_in[3];
  const float* Wq_b  = (const float*)d_in[4];
  const float* Wk_w  = (const float*)d_in[5];
  const float* Wk_b  = (const float*)d_in[6];
  const float* Wv_w  = (const float*)d_in[7];
  const float* Wv_b  = (const float*)d_in[8];
  const float* Wo_w  = (const float*)d_in[9];
  const float* Wo_b  = (const float*)d_in[10];

  char* ws = (char*)d_ws;
  char* dob = (char*)d_out;
  ushort* Qh  = (ushort*)(ws);                 // [0,8) MB
  ushort* Kh  = (ushort*)(ws + (8u  << 20));   // [8,16)
  ushort* Vt  = (ushort*)(ws + (16u << 20));   // [16,24)
  ushort* AO  = (ushort*)(ws + (24u << 20));   // [24,32) late (pass_b)
  ushort* qbf = (ushort*)(ws + (32u << 20));   // [32,40) dead after gemm_qkv
  ushort* kbf = (ushort*)(ws + (40u << 20));   // [40,48) dead after gemm_qkv
  ushort* Wob = (ushort*)(ws + (48u << 20));   // [48,50) survives to gemm_out
  // d_out scratch (dead until pass_a writes rden over all of d_out):
  ushort* vbf = (ushort*)(dob);                // [0,8) MB of d_out
  ushort* Wqb = (ushort*)(dob + (8u  << 20));  // [8,10)
  ushort* Wkb = (ushort*)(dob + (10u << 20));  // [10,12)
  ushort* Wvb = (ushort*)(dob + (12u << 20));  // [12,14)
  __half* rdn = (__half*)d_out;                // 16 MB exactly; dead before gemm_out

  const int NA = 2 * LL * DM;   // 4194304
  const int NW = DM * DM;       // 1048576

  // single conversion launch: q,k,v + Wq,Wk,Wv,Wo
  cvt7<<<(3 * NA + 4 * NW) / 1024, 256, 0, stream>>>(
      query, qbf, NA, key, kbf, NA, value, vbf, NA,
      Wq_w, Wqb, NW, Wk_w, Wkb, NW, Wv_w, Wvb, NW, Wo_w, Wob, NW);

  gemm_qkv<<<dim3(32, 8, 3), 256, 0, stream>>>(qbf, Wqb, Wq_b, Qh,
                                               kbf, Wkb, Wk_b, Kh,
                                               vbf, Wvb, Wv_b, Vt);

  pass_a_m<<<dim3(16, 16, 2), 256, 0, stream>>>(Qh, Kh, rdn);
  pass_b_m<<<dim3(8, NH, 2), 512, 0, stream>>>(Qh, Kh, Vt, rdn, AO);

  gemm_out<<<dim3(64, 8), 256, 0, stream>>>(AO, Wob, Wo_b, (float*)d_out);
}

// Round 20
// 189.484 us; speedup vs baseline: 1.0784x; 1.0784x over previous
//
// CategoryAttention (softmax over HEADS axis). Round 20 = round 18 verbatim
// (best verified: 190us). Round-19 wide-wave (32q/wave) falsified: VGPR 100 +
// 69.6KB LDS -> 1 block/CU, occupancy 41->21.5%, pass_b 81->92.5us.
// Seven pass_b structural variants all lose to this 8-wave/16q/2-stage form.
#include <hip/hip_runtime.h>
#include <hip/hip_bf16.h>
#include <hip/hip_fp16.h>

#define DM 1024
#define NH 16
#define HD 64
#define LL 2048

typedef __attribute__((ext_vector_type(8))) short bf16x8;
typedef __attribute__((ext_vector_type(4))) float f32x4;

#define MFMA16(a,b,c) __builtin_amdgcn_mfma_f32_16x16x32_bf16((a),(b),(c),0,0,0)

// async global->LDS, 16B per lane; dst wave-uniform, src per-lane.
#define GL16(g, l) __builtin_amdgcn_global_load_lds( \
    (const __attribute__((address_space(1))) unsigned int*)(g), \
    (__attribute__((address_space(3))) unsigned int*)(l), 16, 0, 0)

__device__ __forceinline__ ushort f2bf(float f) {
  union { float f; unsigned int u; } v; v.f = f;
  unsigned int u = v.u + 0x7fffu + ((v.u >> 16) & 1u);
  return (ushort)(u >> 16);
}

// ---- batched fp32 -> bf16 convert over up to 7 regions (one launch) ----
__global__ __launch_bounds__(256) void cvt7(const float* __restrict__ s0, ushort* __restrict__ d0, int n0,
                                            const float* __restrict__ s1, ushort* __restrict__ d1, int n1,
                                            const float* __restrict__ s2, ushort* __restrict__ d2, int n2,
                                            const float* __restrict__ s3, ushort* __restrict__ d3, int n3,
                                            const float* __restrict__ s4, ushort* __restrict__ d4, int n4,
                                            const float* __restrict__ s5, ushort* __restrict__ d5, int n5,
                                            const float* __restrict__ s6, ushort* __restrict__ d6, int n6) {
  int i = (blockIdx.x * 256 + threadIdx.x) * 4;
  const float* s; ushort* d;
  if (i < n0) { s = s0; d = d0; }
  else if ((i -= n0) < n1) { s = s1; d = d1; }
  else if ((i -= n1) < n2) { s = s2; d = d2; }
  else if ((i -= n2) < n3) { s = s3; d = d3; }
  else if ((i -= n3) < n4) { s = s4; d = d4; }
  else if ((i -= n4) < n5) { s = s5; d = d5; }
  else if ((i -= n5) < n6) { s = s6; d = d6; }
  else return;
  float4 v = *(const float4*)(s + i);
  union { ushort u[4]; unsigned long long ll; } o;
  o.u[0] = f2bf(v.x); o.u[1] = f2bf(v.y); o.u[2] = f2bf(v.z); o.u[3] = f2bf(v.w);
  *(unsigned long long*)(d + i) = o.ll;
}

// ---- fused QKV projection GEMM, 128x128 tile ----
// z=0 Q (alpha=0.125), z=1 K, z=2 V (transposed out).
__global__ __launch_bounds__(256) void gemm_qkv(const ushort* __restrict__ qA, const ushort* __restrict__ qW,
                                                const float* __restrict__ qb, ushort* __restrict__ qO,
                                                const ushort* __restrict__ kA, const ushort* __restrict__ kW,
                                                const float* __restrict__ kb, ushort* __restrict__ kO,
                                                const ushort* __restrict__ vA, const ushort* __restrict__ vW,
                                                const float* __restrict__ vb, ushort* __restrict__ vO) {
  __shared__ ushort lA[2][128][64];
  __shared__ ushort lB[2][128][64];
  const int z = blockIdx.z;
  const ushort* Ab; const ushort* Wb; const float* bias; ushort* outp;
  float alpha; bool trans;
  if (z == 0)      { Ab = qA; Wb = qW; bias = qb; outp = qO; alpha = 0.125f; trans = false; }
  else if (z == 1) { Ab = kA; Wb = kW; bias = kb; outp = kO; alpha = 1.0f;   trans = false; }
  else             { Ab = vA; Wb = vW; bias = vb; outp = vO; alpha = 1.0f;   trans = true;  }

  const int m0 = blockIdx.x * 128, n0 = blockIdx.y * 128;
  const int t = threadIdx.x;
  const int w = t >> 6, lane = t & 63, lr = lane & 15, lg = lane >> 4;
  const int wm = (w >> 1) * 64, wn = (w & 1) * 64;
  const int lrow8 = lane >> 3;
  const int scol = ((lane & 7) ^ lrow8) * 8;

  f32x4 acc[4][4];
  #pragma unroll
  for (int i = 0; i < 4; ++i)
    #pragma unroll
    for (int j = 0; j < 4; ++j) acc[i][j] = (f32x4){0.f, 0.f, 0.f, 0.f};

  #pragma unroll
  for (int c = 0; c < 4; ++c) {
    GL16(Ab + (m0 + w * 32 + c * 8 + lrow8) * DM + scol, &lA[0][w * 32 + c * 8][0]);
    GL16(Wb + (n0 + w * 32 + c * 8 + lrow8) * DM + scol, &lB[0][w * 32 + c * 8][0]);
  }
  __syncthreads();

  int cur = 0;
  for (int k0 = 0; k0 < DM; k0 += 64) {
    if (k0 + 64 < DM) {
      #pragma unroll
      for (int c = 0; c < 4; ++c) {
        GL16(Ab + (m0 + w * 32 + c * 8 + lrow8) * DM + k0 + 64 + scol, &lA[cur ^ 1][w * 32 + c * 8][0]);
        GL16(Wb + (n0 + w * 32 + c * 8 + lrow8) * DM + k0 + 64 + scol, &lB[cur ^ 1][w * 32 + c * 8][0]);
      }
    }
    #pragma unroll
    for (int ks = 0; ks < 2; ++ks) {
      bf16x8 aF[4], bF[4];
      #pragma unroll
      for (int i = 0; i < 4; ++i)
        aF[i] = *(const bf16x8*)&lA[cur][wm + i * 16 + lr][(((ks * 4 + lg) ^ (lr & 7)) * 8)];
      #pragma unroll
      for (int j = 0; j < 4; ++j)
        bF[j] = *(const bf16x8*)&lB[cur][wn + j * 16 + lr][(((ks * 4 + lg) ^ (lr & 7)) * 8)];
      #pragma unroll
      for (int i = 0; i < 4; ++i)
        #pragma unroll
        for (int j = 0; j < 4; ++j)
          acc[i][j] = MFMA16(aF[i], bF[j], acc[i][j]);
    }
    __syncthreads();
    cur ^= 1;
  }

  #pragma unroll
  for (int i = 0; i < 4; ++i)
    #pragma unroll
    for (int j = 0; j < 4; ++j)
      #pragma unroll
      for (int r = 0; r < 4; ++r) {
        int m = m0 + wm + i * 16 + lg * 4 + r;
        int n = n0 + wn + j * 16 + lr;
        float v = (acc[i][j][r] + bias[n]) * alpha;
        int b = m >> 11, q = m & 2047, h = n >> 6, d = n & 63;
        if (!trans)
          outp[((b * NH + h) * LL + q) * HD + d] = f2bf(v);
        else
          outp[((b * NH + h) * HD + d) * LL + q] = f2bf(v);
      }
}

// ---- output GEMM: 64x128 tile, fp32 out ----
__global__ __launch_bounds__(256) void gemm_out(const ushort* __restrict__ Ab,
                                                const ushort* __restrict__ Wb,
                                                const float* __restrict__ bias,
                                                float* __restrict__ outf) {
  __shared__ ushort lA[2][64][64];
  __shared__ ushort lB[2][128][64];
  const int m0 = blockIdx.x * 64, n0 = blockIdx.y * 128;
  const int t = threadIdx.x;
  const int w = t >> 6, lane = t & 63, lr = lane & 15, lg = lane >> 4;
  const int wm = (w >> 1) * 32, wn = (w & 1) * 64;
  const int lrow8 = lane >> 3;
  const int scol = ((lane & 7) ^ lrow8) * 8;

  f32x4 acc[2][4];
  #pragma unroll
  for (int i = 0; i < 2; ++i)
    #pragma unroll
    for (int j = 0; j < 4; ++j) acc[i][j] = (f32x4){0.f, 0.f, 0.f, 0.f};

  #pragma unroll
  for (int c = 0; c < 2; ++c)
    GL16(Ab + (m0 + w * 16 + c * 8 + lrow8) * DM + scol, &lA[0][w * 16 + c * 8][0]);
  #pragma unroll
  for (int c = 0; c < 4; ++c)
    GL16(Wb + (n0 + w * 32 + c * 8 + lrow8) * DM + scol, &lB[0][w * 32 + c * 8][0]);
  __syncthreads();

  int cur = 0;
  for (int k0 = 0; k0 < DM; k0 += 64) {
    if (k0 + 64 < DM) {
      #pragma unroll
      for (int c = 0; c < 2; ++c)
        GL16(Ab + (m0 + w * 16 + c * 8 + lrow8) * DM + k0 + 64 + scol, &lA[cur ^ 1][w * 16 + c * 8][0]);
      #pragma unroll
      for (int c = 0; c < 4; ++c)
        GL16(Wb + (n0 + w * 32 + c * 8 + lrow8) * DM + k0 + 64 + scol, &lB[cur ^ 1][w * 32 + c * 8][0]);
    }
    #pragma unroll
    for (int ks = 0; ks < 2; ++ks) {
      bf16x8 aF[2], bF[4];
      #pragma unroll
      for (int i = 0; i < 2; ++i)
        aF[i] = *(const bf16x8*)&lA[cur][wm + i * 16 + lr][(((ks * 4 + lg) ^ (lr & 7)) * 8)];
      #pragma unroll
      for (int j = 0; j < 4; ++j)
        bF[j] = *(const bf16x8*)&lB[cur][wn + j * 16 + lr][(((ks * 4 + lg) ^ (lr & 7)) * 8)];
      #pragma unroll
      for (int i = 0; i < 2; ++i)
        #pragma unroll
        for (int j = 0; j < 4; ++j)
          acc[i][j] = MFMA16(aF[i], bF[j], acc[i][j]);
    }
    __syncthreads();
    cur ^= 1;
  }

  #pragma unroll
  for (int i = 0; i < 2; ++i)
    #pragma unroll
    for (int j = 0; j < 4; ++j)
      #pragma unroll
      for (int r = 0; r < 4; ++r) {
        int m = m0 + wm + i * 16 + lg * 4 + r;
        int n = n0 + wn + j * 16 + lr;
        outf[m * DM + n] = acc[i][j][r] + bias[n];
      }
}

// ---- Pass A (MFMA, swapped): rdenH[b][q][k] = 1 / sum_h exp(<Qh,Kh>) ----
// + XCD-bijective swizzle (4 q-rows x 16 k-cols per XCD -> panels L2-resident)
__global__ __launch_bounds__(256) void pass_a_m(const ushort* __restrict__ Qh,
                                                const ushort* __restrict__ Kh,
                                                __half* __restrict__ rdenH) {
  __shared__ ushort lQ[2][128][64];
  __shared__ ushort lK[2][128][64];
  const int fid = blockIdx.x + 16 * (blockIdx.y + 16 * blockIdx.z);
  const int nid = (fid & 7) * 64 + (fid >> 3);
  const int k0 = (nid & 15) * 128;
  const int q0 = ((nid >> 4) & 15) * 128;
  const int b  = nid >> 8;
  const int t = threadIdx.x, w = t >> 6, lane = t & 63, lr = lane & 15, lg = lane >> 4;
  const int lrow8 = lane >> 3;
  const int scol = ((lane & 7) ^ lrow8) * 8;

  f32x4 acc[2][8];
  #pragma unroll
  for (int i = 0; i < 2; ++i)
    #pragma unroll
    for (int j = 0; j < 8; ++j) acc[i][j] = (f32x4){0.f, 0.f, 0.f, 0.f};

  #pragma unroll
  for (int c = 0; c < 4; ++c) {
    GL16(Qh + ((b * NH) * LL + q0 + w * 32 + c * 8 + lrow8) * HD + scol, &lQ[0][w * 32 + c * 8][0]);
    GL16(Kh + ((b * NH) * LL + k0 + w * 32 + c * 8 + lrow8) * HD + scol, &lK[0][w * 32 + c * 8][0]);
  }
  __syncthreads();

  int cur = 0;
  for (int h = 0; h < NH; ++h) {
    if (h + 1 < NH) {
      #pragma unroll
      for (int c = 0; c < 4; ++c) {
        GL16(Qh + ((b * NH + h + 1) * LL + q0 + w * 32 + c * 8 + lrow8) * HD + scol, &lQ[cur ^ 1][w * 32 + c * 8][0]);
        GL16(Kh + ((b * NH + h + 1) * LL + k0 + w * 32 + c * 8 + lrow8) * HD + scol, &lK[cur ^ 1][w * 32 + c * 8][0]);
      }
    }
    #pragma unroll
    for (int i = 0; i < 2; ++i) {
      int qrow = w * 32 + i * 16 + lr;
      bf16x8 a0 = *(const bf16x8*)&lQ[cur][qrow][((lg ^ (lr & 7)) * 8)];
      bf16x8 a1 = *(const bf16x8*)&lQ[cur][qrow][(((4 + lg) ^ (lr & 7)) * 8)];
      #pragma unroll
      for (int j = 0; j < 8; ++j) {
        int krow = j * 16 + lr;
        bf16x8 b0 = *(const bf16x8*)&lK[cur][krow][((lg ^ (lr & 7)) * 8)];
        bf16x8 b1 = *(const bf16x8*)&lK[cur][krow][(((4 + lg) ^ (lr & 7)) * 8)];
        f32x4 e = {0.f, 0.f, 0.f, 0.f};
        e = MFMA16(b0, a0, e);   // swapped: D[k][q]
        e = MFMA16(b1, a1, e);
        #pragma unroll
        for (int r = 0; r < 4; ++r) acc[i][j][r] += __expf(e[r]);
      }
    }
    __syncthreads();
    cur ^= 1;
  }

  #pragma unroll
  for (int i = 0; i < 2; ++i)
    #pragma unroll
    for (int j = 0; j < 8; ++j) {
      int q = q0 + w * 32 + i * 16 + lr;
      int k = k0 + j * 16 + lg * 4;
      union { __half2 h2[2]; uint2 u; } pk;
      pk.h2[0] = __floats2half2_rn(__builtin_amdgcn_rcpf(acc[i][j][0]),
                                   __builtin_amdgcn_rcpf(acc[i][j][1]));
      pk.h2[1] = __floats2half2_rn(__builtin_amdgcn_rcpf(acc[i][j][2]),
                                   __builtin_amdgcn_rcpf(acc[i][j][3]));
      *(uint2*)&rdenH[(size_t)(b * LL + q) * LL + k] = pk.u;
    }
}

// ---- Pass B: 8 waves x 16q, 2-stage pipeline, single wave-private P buffer ----
// (round-11 form) + XCD-bijective block swizzle.
#define PB_BODY(PH)                                                              \
  {                                                                              \
    const int T = tt + PH;                                                       \
    const int k0 = T * 64;                                                       \
    uint2 rdN[4];                                                                \
    if (T + 1 < 32) {                                                            \
      GL16(Kh + (bh * LL + k0 + 64 + w * 8 + lrow8) * HD + scol,                 \
           &lK[PH ^ 1][w * 8][0]);                                               \
      GL16(Vt + (bh * HD + w * 8 + lrow8) * LL + k0 + 64 + scol,                 \
           &lV[PH ^ 1][w * 8][0]);                                               \
      _Pragma("unroll")                                                          \
      for (int j = 0; j < 4; ++j)                                                \
        rdN[j] = *(const uint2*)(rrow + k0 + 64 + j * 16 + lg * 4);              \
    }                                                                            \
    __builtin_amdgcn_s_setprio(1);                                               \
    if (T > 0) {                                                                 \
      bf16x8 aP0 = *(const bf16x8*)&U.p[w][lr][lg * 8];                          \
      bf16x8 aP1 = *(const bf16x8*)&U.p[w][lr][32 + lg * 8];                     \
      _Pragma("unroll")                                                          \
      for (int j = 0; j < 4; ++j) {                                              \
        accO[j] = MFMA16(aP0, vF0[j], accO[j]);                                  \
        accO[j] = MFMA16(aP1, vF1[j], accO[j]);                                  \
      }                                                                          \
    }                                                                            \
    f32x4 e[4];                                                                  \
    _Pragma("unroll")                                                            \
    for (int j = 0; j < 4; ++j) {                                                \
      int krow = j * 16 + lr;                                                    \
      bf16x8 kf0 = *(const bf16x8*)&lK[PH][krow][((lg ^ (lr & 7)) * 8)];         \
      bf16x8 kf1 = *(const bf16x8*)&lK[PH][krow][(((4 + lg) ^ (lr & 7)) * 8)];   \
      e[j] = (f32x4){0.f, 0.f, 0.f, 0.f};                                        \
      e[j] = MFMA16(kf0, aQ0, e[j]);                                             \
      e[j] = MFMA16(kf1, aQ1, e[j]);                                             \
    }                                                                            \
    __builtin_amdgcn_s_setprio(0);                                               \
    _Pragma("unroll")                                                            \
    for (int j = 0; j < 4; ++j) {                                                \
      int vrow = j * 16 + lr;                                                    \
      vF0[j] = *(const bf16x8*)&lV[PH][vrow][((lg ^ (lr & 7)) * 8)];             \
      vF1[j] = *(const bf16x8*)&lV[PH][vrow][(((4 + lg) ^ (lr & 7)) * 8)];       \
    }                                                                            \
    _Pragma("unroll")                                                            \
    for (int j = 0; j < 4; ++j) {                                                \
      float2 f0 = __half22float2(*reinterpret_cast<const __half2*>(&rdC[j].x));  \
      float2 f1 = __half22float2(*reinterpret_cast<const __half2*>(&rdC[j].y));  \
      union { __hip_bfloat162 b2[2]; uint2 u; } pk;                              \
      pk.b2[0] = __float22bfloat162_rn(make_float2(__expf(e[j][0]) * f0.x,       \
                                                   __expf(e[j][1]) * f0.y));     \
      pk.b2[1] = __float22bfloat162_rn(make_float2(__expf(e[j][2]) * f1.x,       \
                                                   __expf(e[j][3]) * f1.y));     \
      *(uint2*)&U.p[w][lr][j * 16 + lg * 4] = pk.u;                              \
    }                                                                            \
    if (T + 1 < 32) {                                                            \
      _Pragma("unroll")                                                          \
      for (int j = 0; j < 4; ++j) rdC[j] = rdN[j];                               \
    }                                                                            \
    __syncthreads();                                                             \
  }

__global__ __launch_bounds__(512, 4) void pass_b_m(const ushort* __restrict__ Qh,
                                                   const ushort* __restrict__ Kh,
                                                   const ushort* __restrict__ Vt,
                                                   const __half* __restrict__ rdenH,
                                                   ushort* __restrict__ AO) {
  __shared__ union UQP { ushort q[128][64]; ushort p[8][16][72]; } U;
  __shared__ ushort lK[2][64][64];
  __shared__ ushort lV[2][64][64];
  // XCD-bijective swizzle: 512 blocks, 4 complete heads per XCD (K/V L2-fit).
  const int fid = blockIdx.x + 16 * (blockIdx.y + NH * blockIdx.z);
  const int nid = (fid & 7) * 64 + (fid >> 3);
  const int q0 = (nid & 15) * 128;
  const int h  = (nid >> 4) & 15;
  const int b  = nid >> 8;
  const int t = threadIdx.x, w = t >> 6, lane = t & 63, lr = lane & 15, lg = lane >> 4;
  const int lrow8 = lane >> 3;
  const int scol = ((lane & 7) ^ lrow8) * 8;
  const int bh = b * NH + h;

  // stage Q (128 rows, linear)
  #pragma unroll
  for (int u = 0; u < 2; ++u) {
    int c = u * 512 + t;
    int row = c >> 3, col = (c & 7) * 8;
    *(bf16x8*)&U.q[row][col] = *(const bf16x8*)&Qh[(bh * LL + q0 + row) * HD + col];
  }
  // prologue K/V tile 0: wave w stages rows [w*8, w*8+8)
  GL16(Kh + (bh * LL + w * 8 + lrow8) * HD + scol, &lK[0][w * 8][0]);
  GL16(Vt + (bh * HD + w * 8 + lrow8) * LL + scol, &lV[0][w * 8][0]);
  // rden prologue (tile 0)
  const int qg = q0 + w * 16 + lr;
  const __half* rrow = rdenH + (size_t)(b * LL + qg) * LL;
  uint2 rdC[4];
  #pragma unroll
  for (int j = 0; j < 4; ++j) rdC[j] = *(const uint2*)(rrow + j * 16 + lg * 4);
  __syncthreads();

  bf16x8 aQ0 = *(const bf16x8*)&U.q[w * 16 + lr][lg * 8];
  bf16x8 aQ1 = *(const bf16x8*)&U.q[w * 16 + lr][32 + lg * 8];
  __syncthreads();   // Q reads complete before any U.p write

  f32x4 accO[4];
  #pragma unroll
  for (int j = 0; j < 4; ++j) accO[j] = (f32x4){0.f, 0.f, 0.f, 0.f};
  bf16x8 vF0[4], vF1[4];

  for (int tt = 0; tt < 32; tt += 2) {
    PB_BODY(0)
    PB_BODY(1)
  }

  // drain: PV(31) -- P in U.p, V frags in regs
  {
    bf16x8 aP0 = *(const bf16x8*)&U.p[w][lr][lg * 8];
    bf16x8 aP1 = *(const bf16x8*)&U.p[w][lr][32 + lg * 8];
    #pragma unroll
    for (int j = 0; j < 4; ++j) {
      accO[j] = MFMA16(aP0, vF0[j], accO[j]);
      accO[j] = MFMA16(aP1, vF1[j], accO[j]);
    }
  }

  #pragma unroll
  for (int j = 0; j < 4; ++j)
    #pragma unroll
    for (int r = 0; r < 4; ++r) {
      int q = q0 + w * 16 + lg * 4 + r;
      int d = j * 16 + lr;
      AO[(b * LL + q) * DM + h * HD + d] = f2bf(accO[j][r]);
    }
}

extern "C" void kernel_launch(void* const* d_in, const int* in_sizes, int n_in,
                              void* d_out, int out_size, void* d_ws, size_t ws_size,
                              hipStream_t stream) {
  const float* query = (const float*)d_in[0];
  const float* key   = (const float*)d_in[1];
  const float* value = (const float*)d_in[2];
  const float* Wq_w  = (const float*)d_in[3];
  const float* Wq_b  = (const float*)d_in[4];
  const float* Wk_w  = (const float*)d_in[5];
  const float* Wk_b  = (const float*)d_in[6];
  const float* Wv_w  = (const float*)d_in[7];
  const float* Wv_b  = (const float*)d_in[8];
  const float* Wo_w  = (const float*)d_in[9];
  const float* Wo_b  = (const float*)d_in[10];

  char* ws = (char*)d_ws;
  char* dob = (char*)d_out;
  ushort* Qh  = (ushort*)(ws);                 // [0,8) MB
  ushort* Kh  = (ushort*)(ws + (8u  << 20));   // [8,16)
  ushort* Vt  = (ushort*)(ws + (16u << 20));   // [16,24)
  ushort* AO  = (ushort*)(ws + (24u << 20));   // [24,32) late (pass_b)
  ushort* qbf = (ushort*)(ws + (32u << 20));   // [32,40) dead after gemm_qkv
  ushort* kbf = (ushort*)(ws + (40u << 20));   // [40,48) dead after gemm_qkv
  ushort* Wob = (ushort*)(ws + (48u << 20));   // [48,50) survives to gemm_out
  // d_out scratch (dead until pass_a writes rden over all of d_out):
  ushort* vbf = (ushort*)(dob);                // [0,8) MB of d_out
  ushort* Wqb = (ushort*)(dob + (8u  << 20));  // [8,10)
  ushort* Wkb = (ushort*)(dob + (10u << 20));  // [10,12)
  ushort* Wvb = (ushort*)(dob + (12u << 20));  // [12,14)
  __half* rdn = (__half*)d_out;                // 16 MB exactly; dead before gemm_out

  const int NA = 2 * LL * DM;   // 4194304
  const int NW = DM * DM;       // 1048576

  // single conversion launch: q,k,v + Wq,Wk,Wv,Wo
  cvt7<<<(3 * NA + 4 * NW) / 1024, 256, 0, stream>>>(
      query, qbf, NA, key, kbf, NA, value, vbf, NA,
      Wq_w, Wqb, NW, Wk_w, Wkb, NW, Wv_w, Wvb, NW, Wo_w, Wob, NW);

  gemm_qkv<<<dim3(32, 8, 3), 256, 0, stream>>>(qbf, Wqb, Wq_b, Qh,
                                               kbf, Wkb, Wk_b, Kh,
                                               vbf, Wvb, Wv_b, Vt);

  pass_a_m<<<dim3(16, 16, 2), 256, 0, stream>>>(Qh, Kh, rdn);
  pass_b_m<<<dim3(16, NH, 2), 512, 0, stream>>>(Qh, Kh, Vt, rdn, AO);

  gemm_out<<<dim3(64, 8), 256, 0, stream>>>(AO, Wob, Wo_b, (float*)d_out);
}